// Round 1
// baseline (361.416 us; speedup 1.0000x reference)
//
#include <hip/hip_runtime.h>
#include <hip/hip_bf16.h>

#define NROWS 2048
#define CCH   64
#define FDIM  256
#define CF    16384   // C*F
#define EPSV  1e-3f

typedef __attribute__((ext_vector_type(8))) short  short8;
typedef __attribute__((ext_vector_type(4))) float  f32x4;

__device__ __forceinline__ ushort f2bf(float f) {
  union { float f; unsigned u; } v; v.f = f;
  unsigned r = v.u + 0x7fffu + ((v.u >> 16) & 1u);
  return (ushort)(r >> 16);
}
__device__ __forceinline__ float bf2f(ushort u) {
  union { unsigned u; float f; } v; v.u = ((unsigned)u) << 16;
  return v.f;
}

// ---------------- BN stats (column sums over batch dim) ----------------
// fp32 source. grid (16, 32), block 256. Each thread: 4 consecutive cols, 64 rows.
__global__ __launch_bounds__(256) void bn_stats_f32(const float* __restrict__ src,
                                                    float* __restrict__ sum,
                                                    float* __restrict__ sumsq) {
  int cb = blockIdx.x * 256 + threadIdx.x;       // float4 col index 0..4095
  int r0 = blockIdx.y * 64;
  const float4* p = (const float4*)src + (size_t)r0 * (CF / 4) + cb;
  float s0 = 0, s1 = 0, s2 = 0, s3 = 0, q0 = 0, q1 = 0, q2 = 0, q3 = 0;
#pragma unroll 8
  for (int i = 0; i < 64; ++i) {
    float4 v = p[(size_t)i * (CF / 4)];
    s0 += v.x; q0 += v.x * v.x;
    s1 += v.y; q1 += v.y * v.y;
    s2 += v.z; q2 += v.z * v.z;
    s3 += v.w; q3 += v.w * v.w;
  }
  int col = cb * 4;
  atomicAdd(&sum[col + 0], s0); atomicAdd(&sum[col + 1], s1);
  atomicAdd(&sum[col + 2], s2); atomicAdd(&sum[col + 3], s3);
  atomicAdd(&sumsq[col + 0], q0); atomicAdd(&sumsq[col + 1], q1);
  atomicAdd(&sumsq[col + 2], q2); atomicAdd(&sumsq[col + 3], q3);
}

// bf16 source. grid (8, 32), block 256. Each thread: 8 consecutive cols, 64 rows.
__global__ __launch_bounds__(256) void bn_stats_bf16(const ushort* __restrict__ src,
                                                     float* __restrict__ sum,
                                                     float* __restrict__ sumsq) {
  int cb = blockIdx.x * 256 + threadIdx.x;       // uint4 (8 bf16) col index 0..2047
  int r0 = blockIdx.y * 64;
  const uint4* p = (const uint4*)src + (size_t)r0 * (CF / 8) + cb;
  float s[8] = {0, 0, 0, 0, 0, 0, 0, 0};
  float q[8] = {0, 0, 0, 0, 0, 0, 0, 0};
#pragma unroll 4
  for (int i = 0; i < 64; ++i) {
    uint4 v = p[(size_t)i * (CF / 8)];
    unsigned w[4] = {v.x, v.y, v.z, v.w};
#pragma unroll
    for (int j = 0; j < 4; ++j) {
      float a = bf2f((ushort)(w[j] & 0xffffu));
      float b = bf2f((ushort)(w[j] >> 16));
      s[2 * j]     += a; q[2 * j]     += a * a;
      s[2 * j + 1] += b; q[2 * j + 1] += b * b;
    }
  }
  int col = cb * 8;
#pragma unroll
  for (int j = 0; j < 8; ++j) {
    atomicAdd(&sum[col + j], s[j]);
    atomicAdd(&sumsq[col + j], q[j]);
  }
}

__global__ __launch_bounds__(256) void bn_finalize(const float* __restrict__ sum,
                                                   const float* __restrict__ sumsq,
                                                   const float* __restrict__ g,
                                                   const float* __restrict__ be,
                                                   float* __restrict__ scale,
                                                   float* __restrict__ shift) {
  int i = blockIdx.x * 256 + threadIdx.x;        // grid 64
  float mean = sum[i] * (1.0f / NROWS);
  float var  = sumsq[i] * (1.0f / NROWS) - mean * mean;
  float sc   = g[i] * rsqrtf(var + EPSV);
  scale[i] = sc;
  shift[i] = be[i] - mean * sc;
}

// ---------------- BN apply + ReLU -> bf16 ----------------
__global__ __launch_bounds__(256) void bn_apply_f32(const float* __restrict__ x,
                                                    const float* __restrict__ scale,
                                                    const float* __restrict__ shift,
                                                    ushort* __restrict__ o) {
  size_t stride = (size_t)gridDim.x * blockDim.x;
  const size_t total4 = (size_t)NROWS * CF / 4;
  for (size_t i = (size_t)blockIdx.x * 256 + threadIdx.x; i < total4; i += stride) {
    float4 v = ((const float4*)x)[i];
    int col = (int)(i & (CF / 4 - 1)) * 4;
    float a = fmaxf(fmaf(v.x, scale[col + 0], shift[col + 0]), 0.f);
    float b = fmaxf(fmaf(v.y, scale[col + 1], shift[col + 1]), 0.f);
    float c = fmaxf(fmaf(v.z, scale[col + 2], shift[col + 2]), 0.f);
    float d = fmaxf(fmaf(v.w, scale[col + 3], shift[col + 3]), 0.f);
    ushort4 u;
    u.x = f2bf(a); u.y = f2bf(b); u.z = f2bf(c); u.w = f2bf(d);
    ((ushort4*)o)[i] = u;
  }
}

__global__ __launch_bounds__(256) void bn_apply_bf16(const ushort* __restrict__ y,
                                                     const float* __restrict__ scale,
                                                     const float* __restrict__ shift,
                                                     ushort* __restrict__ o) {
  size_t stride = (size_t)gridDim.x * blockDim.x;
  const size_t total8 = (size_t)NROWS * CF / 8;
  for (size_t i = (size_t)blockIdx.x * 256 + threadIdx.x; i < total8; i += stride) {
    uint4 v = ((const uint4*)y)[i];
    int col = (int)(i & (CF / 8 - 1)) * 8;
    unsigned w[4] = {v.x, v.y, v.z, v.w};
    unsigned res[4];
#pragma unroll
    for (int j = 0; j < 4; ++j) {
      float a = fmaxf(fmaf(bf2f((ushort)(w[j] & 0xffffu)), scale[col + 2 * j], shift[col + 2 * j]), 0.f);
      float b = fmaxf(fmaf(bf2f((ushort)(w[j] >> 16)), scale[col + 2 * j + 1], shift[col + 2 * j + 1]), 0.f);
      res[j] = (unsigned)f2bf(a) | ((unsigned)f2bf(b) << 16);
    }
    uint4 r; r.x = res[0]; r.y = res[1]; r.z = res[2]; r.w = res[3];
    ((uint4*)o)[i] = r;
  }
}

// ---------------- weight f32 -> bf16 ----------------
__global__ __launch_bounds__(256) void cvt_f32_bf16(const float* __restrict__ w,
                                                    ushort* __restrict__ o, int n4) {
  size_t stride = (size_t)gridDim.x * blockDim.x;
  for (size_t i = (size_t)blockIdx.x * 256 + threadIdx.x; i < (size_t)n4; i += stride) {
    float4 v = ((const float4*)w)[i];
    ushort4 u;
    u.x = f2bf(v.x); u.y = f2bf(v.y); u.z = f2bf(v.z); u.w = f2bf(v.w);
    ((ushort4*)o)[i] = u;
  }
}

// ---------------- batched channel GEMM, bf16 MFMA ----------------
// Per channel c: out[n,o] = sum_f A[n, c*256+f] * W[c, o, f] (+ bias[c,o])
// MODE 0: Ybf[n, c*256+o] = bf16(acc + bias)
// MODE 1: outf[n, c*256+o] = xres[...] + acc + bias
// Tile: BM=128, BN=128, BK=32. 4 waves in 2x2; each wave 64x64 via 4x4 frags.
#define LDP 40   // padded LDS row (elements): 32 + 8 -> 80B stride, 2-way max conflict
template <int MODE>
__global__ __launch_bounds__(256) void gemm_ch(const ushort* __restrict__ A,
                                               const ushort* __restrict__ W,
                                               const float* __restrict__ bias,
                                               const float* __restrict__ xres,
                                               ushort* __restrict__ Ybf,
                                               float* __restrict__ outf) {
  __shared__ __align__(16) ushort As[128 * LDP];
  __shared__ __align__(16) ushort Bs[128 * LDP];

  const int c  = blockIdx.z;
  const int bm = blockIdx.x;   // 0..15
  const int bn = blockIdx.y;   // 0..1
  const int t  = threadIdx.x;
  const int lane = t & 63, wid = t >> 6;
  const int wr = wid >> 1, wc = wid & 1;

  const ushort* Abase = A + (size_t)(bm * 128) * CF + c * FDIM;
  const ushort* Wbase = W + ((size_t)c * FDIM + bn * 128) * FDIM;

  f32x4 acc[4][4];
#pragma unroll
  for (int m = 0; m < 4; ++m)
#pragma unroll
    for (int n = 0; n < 4; ++n) acc[m][n] = (f32x4){0.f, 0.f, 0.f, 0.f};

  const int row  = t >> 2;         // 0..63
  const int colv = (t & 3) * 8;    // 0,8,16,24

  for (int kt = 0; kt < 8; ++kt) {
    const int k0 = kt * 32;
    uint4 a0 = *(const uint4*)(Abase + (size_t)row * CF + k0 + colv);
    uint4 a1 = *(const uint4*)(Abase + (size_t)(row + 64) * CF + k0 + colv);
    uint4 b0 = *(const uint4*)(Wbase + (size_t)row * FDIM + k0 + colv);
    uint4 b1 = *(const uint4*)(Wbase + (size_t)(row + 64) * FDIM + k0 + colv);
    __syncthreads();  // previous iter's LDS reads done before overwrite
    *(uint4*)&As[row * LDP + colv]        = a0;
    *(uint4*)&As[(row + 64) * LDP + colv] = a1;
    *(uint4*)&Bs[row * LDP + colv]        = b0;
    *(uint4*)&Bs[(row + 64) * LDP + colv] = b1;
    __syncthreads();

    short8 af[4], bf[4];
#pragma unroll
    for (int m = 0; m < 4; ++m)
      af[m] = *(const short8*)&As[(wr * 64 + m * 16 + (lane & 15)) * LDP + (lane >> 4) * 8];
#pragma unroll
    for (int n = 0; n < 4; ++n)
      bf[n] = *(const short8*)&Bs[(wc * 64 + n * 16 + (lane & 15)) * LDP + (lane >> 4) * 8];
#pragma unroll
    for (int m = 0; m < 4; ++m)
#pragma unroll
      for (int n = 0; n < 4; ++n)
        acc[m][n] = __builtin_amdgcn_mfma_f32_16x16x32_bf16(af[m], bf[n], acc[m][n], 0, 0, 0);
  }

  // epilogue: C/D layout col=lane&15, row=(lane>>4)*4+j (verified m89/m91)
#pragma unroll
  for (int n = 0; n < 4; ++n) {
    const int col = bn * 128 + wc * 64 + n * 16 + (lane & 15);
    const float bb = bias[c * FDIM + col];
#pragma unroll
    for (int m = 0; m < 4; ++m) {
      const int r0 = bm * 128 + wr * 64 + m * 16 + ((lane >> 4) * 4);
#pragma unroll
      for (int j = 0; j < 4; ++j) {
        const float v = acc[m][n][j] + bb;
        const size_t oidx = (size_t)(r0 + j) * CF + c * FDIM + col;
        if (MODE == 0) {
          Ybf[oidx] = f2bf(v);
        } else {
          outf[oidx] = xres[oidx] + v;
        }
      }
    }
  }
}

// ---------------- launch ----------------
extern "C" void kernel_launch(void* const* d_in, const int* in_sizes, int n_in,
                              void* d_out, int out_size, void* d_ws, size_t ws_size,
                              hipStream_t stream) {
  const float* x   = (const float*)d_in[0];
  const float* w0  = (const float*)d_in[1];
  const float* b0  = (const float*)d_in[2];
  const float* w1  = (const float*)d_in[3];
  const float* b1  = (const float*)d_in[4];
  const float* g0  = (const float*)d_in[5];
  const float* be0 = (const float*)d_in[6];
  const float* g1  = (const float*)d_in[7];
  const float* be1 = (const float*)d_in[8];
  float* out = (float*)d_out;

  char* ws = (char*)d_ws;
  const size_t STATS = 16384 * sizeof(float);
  float* sum0   = (float*)(ws + 0 * STATS);
  float* sumsq0 = (float*)(ws + 1 * STATS);
  float* sum1   = (float*)(ws + 2 * STATS);
  float* sumsq1 = (float*)(ws + 3 * STATS);
  float* scale0 = (float*)(ws + 4 * STATS);
  float* shift0 = (float*)(ws + 5 * STATS);
  float* scale1 = (float*)(ws + 6 * STATS);
  float* shift1 = (float*)(ws + 7 * STATS);
  ushort* w0bf = (ushort*)(ws + 8 * STATS);
  ushort* w1bf = w0bf + (size_t)CCH * FDIM * FDIM;
  ushort* tbuf = w1bf + (size_t)CCH * FDIM * FDIM;          // reused for t0 and t1
  ushort* ybf  = tbuf + (size_t)NROWS * CF;

  hipMemsetAsync(ws, 0, 4 * STATS, stream);  // zero the four sum buffers

  const int NW4 = CCH * FDIM * FDIM / 4;
  cvt_f32_bf16<<<1024, 256, 0, stream>>>(w0, w0bf, NW4);
  cvt_f32_bf16<<<1024, 256, 0, stream>>>(w1, w1bf, NW4);

  // BN0 over x
  bn_stats_f32<<<dim3(16, 32), 256, 0, stream>>>(x, sum0, sumsq0);
  bn_finalize<<<64, 256, 0, stream>>>(sum0, sumsq0, g0, be0, scale0, shift0);
  bn_apply_f32<<<2048, 256, 0, stream>>>(x, scale0, shift0, tbuf);

  // linear0 -> ybf (bf16)
  gemm_ch<0><<<dim3(16, 2, CCH), 256, 0, stream>>>(tbuf, w0bf, b0, nullptr, ybf, nullptr);

  // BN1 over ybf
  bn_stats_bf16<<<dim3(8, 32), 256, 0, stream>>>(ybf, sum1, sumsq1);
  bn_finalize<<<64, 256, 0, stream>>>(sum1, sumsq1, g1, be1, scale1, shift1);
  bn_apply_bf16<<<2048, 256, 0, stream>>>(ybf, scale1, shift1, tbuf);

  // linear1 + residual -> out (fp32)
  gemm_ch<1><<<dim3(16, 2, CCH), 256, 0, stream>>>(tbuf, w1bf, b1, x, nullptr, out);
}

// Round 2
// 293.273 us; speedup vs baseline: 1.2324x; 1.2324x over previous
//
#include <hip/hip_runtime.h>
#include <hip/hip_bf16.h>

#define NROWS 2048
#define CCH   64
#define FDIM  256
#define CF    16384   // C*F
#define EPSV  1e-3f

typedef __attribute__((ext_vector_type(8))) short  short8;
typedef __attribute__((ext_vector_type(4))) float  f32x4;

__device__ __forceinline__ ushort f2bf(float f) {
  union { float f; unsigned u; } v; v.f = f;
  unsigned r = v.u + 0x7fffu + ((v.u >> 16) & 1u);
  return (ushort)(r >> 16);
}
__device__ __forceinline__ float bf2f(ushort u) {
  union { unsigned u; float f; } v; v.u = ((unsigned)u) << 16;
  return v.f;
}

// ---------------- BN stats (column sums over batch dim) ----------------
__global__ __launch_bounds__(256) void bn_stats_f32(const float* __restrict__ src,
                                                    float* __restrict__ sum,
                                                    float* __restrict__ sumsq) {
  int cb = blockIdx.x * 256 + threadIdx.x;       // float4 col index 0..4095
  int r0 = blockIdx.y * 64;
  const float4* p = (const float4*)src + (size_t)r0 * (CF / 4) + cb;
  float s0 = 0, s1 = 0, s2 = 0, s3 = 0, q0 = 0, q1 = 0, q2 = 0, q3 = 0;
#pragma unroll 8
  for (int i = 0; i < 64; ++i) {
    float4 v = p[(size_t)i * (CF / 4)];
    s0 += v.x; q0 += v.x * v.x;
    s1 += v.y; q1 += v.y * v.y;
    s2 += v.z; q2 += v.z * v.z;
    s3 += v.w; q3 += v.w * v.w;
  }
  int col = cb * 4;
  atomicAdd(&sum[col + 0], s0); atomicAdd(&sum[col + 1], s1);
  atomicAdd(&sum[col + 2], s2); atomicAdd(&sum[col + 3], s3);
  atomicAdd(&sumsq[col + 0], q0); atomicAdd(&sumsq[col + 1], q1);
  atomicAdd(&sumsq[col + 2], q2); atomicAdd(&sumsq[col + 3], q3);
}

__global__ __launch_bounds__(256) void bn_stats_bf16(const ushort* __restrict__ src,
                                                     float* __restrict__ sum,
                                                     float* __restrict__ sumsq) {
  int cb = blockIdx.x * 256 + threadIdx.x;       // uint4 (8 bf16) col index 0..2047
  int r0 = blockIdx.y * 64;
  const uint4* p = (const uint4*)src + (size_t)r0 * (CF / 8) + cb;
  float s[8] = {0, 0, 0, 0, 0, 0, 0, 0};
  float q[8] = {0, 0, 0, 0, 0, 0, 0, 0};
#pragma unroll 4
  for (int i = 0; i < 64; ++i) {
    uint4 v = p[(size_t)i * (CF / 8)];
    unsigned w[4] = {v.x, v.y, v.z, v.w};
#pragma unroll
    for (int j = 0; j < 4; ++j) {
      float a = bf2f((ushort)(w[j] & 0xffffu));
      float b = bf2f((ushort)(w[j] >> 16));
      s[2 * j]     += a; q[2 * j]     += a * a;
      s[2 * j + 1] += b; q[2 * j + 1] += b * b;
    }
  }
  int col = cb * 8;
#pragma unroll
  for (int j = 0; j < 8; ++j) {
    atomicAdd(&sum[col + j], s[j]);
    atomicAdd(&sumsq[col + j], q[j]);
  }
}

__global__ __launch_bounds__(256) void bn_finalize(const float* __restrict__ sum,
                                                   const float* __restrict__ sumsq,
                                                   const float* __restrict__ g,
                                                   const float* __restrict__ be,
                                                   float* __restrict__ scale,
                                                   float* __restrict__ shift) {
  int i = blockIdx.x * 256 + threadIdx.x;        // grid 64
  float mean = sum[i] * (1.0f / NROWS);
  float var  = sumsq[i] * (1.0f / NROWS) - mean * mean;
  float sc   = g[i] * rsqrtf(var + EPSV);
  scale[i] = sc;
  shift[i] = be[i] - mean * sc;
}

// ---------------- BN apply + ReLU -> bf16 ----------------
__global__ __launch_bounds__(256) void bn_apply_f32(const float* __restrict__ x,
                                                    const float* __restrict__ scale,
                                                    const float* __restrict__ shift,
                                                    ushort* __restrict__ o) {
  size_t stride = (size_t)gridDim.x * blockDim.x;
  const size_t total4 = (size_t)NROWS * CF / 4;
  for (size_t i = (size_t)blockIdx.x * 256 + threadIdx.x; i < total4; i += stride) {
    float4 v = ((const float4*)x)[i];
    int col = (int)(i & (CF / 4 - 1)) * 4;
    float a = fmaxf(fmaf(v.x, scale[col + 0], shift[col + 0]), 0.f);
    float b = fmaxf(fmaf(v.y, scale[col + 1], shift[col + 1]), 0.f);
    float c = fmaxf(fmaf(v.z, scale[col + 2], shift[col + 2]), 0.f);
    float d = fmaxf(fmaf(v.w, scale[col + 3], shift[col + 3]), 0.f);
    ushort4 u;
    u.x = f2bf(a); u.y = f2bf(b); u.z = f2bf(c); u.w = f2bf(d);
    ((ushort4*)o)[i] = u;
  }
}

__global__ __launch_bounds__(256) void bn_apply_bf16(const ushort* __restrict__ y,
                                                     const float* __restrict__ scale,
                                                     const float* __restrict__ shift,
                                                     ushort* __restrict__ o) {
  size_t stride = (size_t)gridDim.x * blockDim.x;
  const size_t total8 = (size_t)NROWS * CF / 8;
  for (size_t i = (size_t)blockIdx.x * 256 + threadIdx.x; i < total8; i += stride) {
    uint4 v = ((const uint4*)y)[i];
    int col = (int)(i & (CF / 8 - 1)) * 8;
    unsigned w[4] = {v.x, v.y, v.z, v.w};
    unsigned res[4];
#pragma unroll
    for (int j = 0; j < 4; ++j) {
      float a = fmaxf(fmaf(bf2f((ushort)(w[j] & 0xffffu)), scale[col + 2 * j], shift[col + 2 * j]), 0.f);
      float b = fmaxf(fmaf(bf2f((ushort)(w[j] >> 16)), scale[col + 2 * j + 1], shift[col + 2 * j + 1]), 0.f);
      res[j] = (unsigned)f2bf(a) | ((unsigned)f2bf(b) << 16);
    }
    uint4 r; r.x = res[0]; r.y = res[1]; r.z = res[2]; r.w = res[3];
    ((uint4*)o)[i] = r;
  }
}

// ---------------- weight f32 -> bf16 ----------------
__global__ __launch_bounds__(256) void cvt_f32_bf16(const float* __restrict__ w,
                                                    ushort* __restrict__ o, int n4) {
  size_t stride = (size_t)gridDim.x * blockDim.x;
  for (size_t i = (size_t)blockIdx.x * 256 + threadIdx.x; i < (size_t)n4; i += stride) {
    float4 v = ((const float4*)w)[i];
    ushort4 u;
    u.x = f2bf(v.x); u.y = f2bf(v.y); u.z = f2bf(v.z); u.w = f2bf(v.w);
    ((ushort4*)o)[i] = u;
  }
}

// ---------------- batched channel GEMM, bf16 MFMA ----------------
// Per channel c: out[n,o] = sum_f A[n, c*256+f] * W[c, o, f] (+ bias[c,o])
// BM=128, BN=128, BK=64 (4 K-steps). 4 waves 2x2, each wave 64x64 = 4x4 frags.
// Staging: global_load_lds dwordx4, linear LDS [128][64] bf16 (128B rows),
// XOR swizzle (T2 / rule #21): phys_byte = log_byte ^ ((row&7)<<4), applied on
// the GLOBAL source (inverse) and on the ds_read address -> 2-way conflicts (free).
template <int MODE>
__global__ __launch_bounds__(256) void gemm_ch(const ushort* __restrict__ A,
                                               const ushort* __restrict__ W,
                                               const float* __restrict__ bias,
                                               const float* __restrict__ xres,
                                               ushort* __restrict__ Ybf,
                                               float* __restrict__ outf) {
  __shared__ __align__(16) ushort As[128 * 64];
  __shared__ __align__(16) ushort Bs[128 * 64];

  const int c  = blockIdx.z;
  const int bm = blockIdx.x;   // 0..15
  const int bn = blockIdx.y;   // 0..1
  const int t  = threadIdx.x;
  const int lane = t & 63, wid = t >> 6;
  const int wr = wid >> 1, wc = wid & 1;

  // staging: chunk i (0..3), thread t covers LDS bytes o = i*4096 + t*16
  // row = i*32 + (t>>3)  (so row&7 == (t>>3)&7, invariant over i)
  // byte-in-row sb = (t&7)*16 ; global byte = sb ^ ((row&7)<<4)
  const int srow = t >> 3;                       // 0..31
  const int sb   = (t & 7) * 16;                 // 0..112
  const int gb   = sb ^ ((srow & 7) << 4);       // swizzled source byte-in-row

  const char* Abytes = (const char*)A;
  const char* Wbytes = (const char*)W;
  char* AsB = (char*)As;
  char* BsB = (char*)Bs;

  f32x4 acc[4][4];
#pragma unroll
  for (int m = 0; m < 4; ++m)
#pragma unroll
    for (int n = 0; n < 4; ++n) acc[m][n] = (f32x4){0.f, 0.f, 0.f, 0.f};

  for (int kt = 0; kt < 4; ++kt) {
    const size_t kofs = (size_t)kt * 64 * 2;     // byte offset of k-slice start
    __syncthreads();                             // prior reads done before overwrite
#pragma unroll
    for (int i = 0; i < 4; ++i) {
      const int row = i * 32 + srow;
      const char* ga = Abytes + ((size_t)(bm * 128 + row) * CF + c * FDIM) * 2 + kofs + gb;
      const char* gw = Wbytes + ((size_t)(c * FDIM + bn * 128 + row) * FDIM) * 2 + kofs + gb;
      __builtin_amdgcn_global_load_lds(
          (const __attribute__((address_space(1))) unsigned*)ga,
          (__attribute__((address_space(3))) unsigned*)(AsB + row * 128 + sb), 16, 0, 0);
      __builtin_amdgcn_global_load_lds(
          (const __attribute__((address_space(1))) unsigned*)gw,
          (__attribute__((address_space(3))) unsigned*)(BsB + row * 128 + sb), 16, 0, 0);
    }
    __syncthreads();                             // drains vmcnt(0) + barrier

#pragma unroll
    for (int s = 0; s < 2; ++s) {
      short8 af[4], bfv[4];
#pragma unroll
      for (int m = 0; m < 4; ++m) {
        const int r = wr * 64 + m * 16 + (lane & 15);
        const int bphys = (s * 64 + (lane >> 4) * 16) ^ ((r & 7) << 4);
        af[m] = *(const short8*)(AsB + r * 128 + bphys);
      }
#pragma unroll
      for (int n = 0; n < 4; ++n) {
        const int r = wc * 64 + n * 16 + (lane & 15);
        const int bphys = (s * 64 + (lane >> 4) * 16) ^ ((r & 7) << 4);
        bfv[n] = *(const short8*)(BsB + r * 128 + bphys);
      }
#pragma unroll
      for (int m = 0; m < 4; ++m)
#pragma unroll
        for (int n = 0; n < 4; ++n)
          acc[m][n] = __builtin_amdgcn_mfma_f32_16x16x32_bf16(af[m], bfv[n], acc[m][n], 0, 0, 0);
    }
  }

  // epilogue: C/D layout col=lane&15, row=(lane>>4)*4+j (verified m89/m91)
#pragma unroll
  for (int n = 0; n < 4; ++n) {
    const int col = bn * 128 + wc * 64 + n * 16 + (lane & 15);
    const float bb = bias[c * FDIM + col];
#pragma unroll
    for (int m = 0; m < 4; ++m) {
      const int r0 = bm * 128 + wr * 64 + m * 16 + ((lane >> 4) * 4);
#pragma unroll
      for (int j = 0; j < 4; ++j) {
        const float v = acc[m][n][j] + bb;
        const size_t oidx = (size_t)(r0 + j) * CF + c * FDIM + col;
        if (MODE == 0) {
          Ybf[oidx] = f2bf(v);
        } else {
          outf[oidx] = xres[oidx] + v;
        }
      }
    }
  }
}

// ---------------- launch ----------------
extern "C" void kernel_launch(void* const* d_in, const int* in_sizes, int n_in,
                              void* d_out, int out_size, void* d_ws, size_t ws_size,
                              hipStream_t stream) {
  const float* x   = (const float*)d_in[0];
  const float* w0  = (const float*)d_in[1];
  const float* b0  = (const float*)d_in[2];
  const float* w1  = (const float*)d_in[3];
  const float* b1  = (const float*)d_in[4];
  const float* g0  = (const float*)d_in[5];
  const float* be0 = (const float*)d_in[6];
  const float* g1  = (const float*)d_in[7];
  const float* be1 = (const float*)d_in[8];
  float* out = (float*)d_out;

  char* ws = (char*)d_ws;
  const size_t STATS = 16384 * sizeof(float);
  float* sum0   = (float*)(ws + 0 * STATS);
  float* sumsq0 = (float*)(ws + 1 * STATS);
  float* sum1   = (float*)(ws + 2 * STATS);
  float* sumsq1 = (float*)(ws + 3 * STATS);
  float* scale0 = (float*)(ws + 4 * STATS);
  float* shift0 = (float*)(ws + 5 * STATS);
  float* scale1 = (float*)(ws + 6 * STATS);
  float* shift1 = (float*)(ws + 7 * STATS);
  ushort* w0bf = (ushort*)(ws + 8 * STATS);
  ushort* w1bf = w0bf + (size_t)CCH * FDIM * FDIM;
  ushort* tbuf = w1bf + (size_t)CCH * FDIM * FDIM;          // reused for t0 and t1
  ushort* ybf  = tbuf + (size_t)NROWS * CF;

  hipMemsetAsync(ws, 0, 4 * STATS, stream);  // zero the four sum buffers

  const int NW4 = CCH * FDIM * FDIM / 4;
  cvt_f32_bf16<<<1024, 256, 0, stream>>>(w0, w0bf, NW4);
  cvt_f32_bf16<<<1024, 256, 0, stream>>>(w1, w1bf, NW4);

  // BN0 over x
  bn_stats_f32<<<dim3(16, 32), 256, 0, stream>>>(x, sum0, sumsq0);
  bn_finalize<<<64, 256, 0, stream>>>(sum0, sumsq0, g0, be0, scale0, shift0);
  bn_apply_f32<<<2048, 256, 0, stream>>>(x, scale0, shift0, tbuf);

  // linear0 -> ybf (bf16)
  gemm_ch<0><<<dim3(16, 2, CCH), 256, 0, stream>>>(tbuf, w0bf, b0, nullptr, ybf, nullptr);

  // BN1 over ybf
  bn_stats_bf16<<<dim3(8, 32), 256, 0, stream>>>(ybf, sum1, sumsq1);
  bn_finalize<<<64, 256, 0, stream>>>(sum1, sumsq1, g1, be1, scale1, shift1);
  bn_apply_bf16<<<2048, 256, 0, stream>>>(ybf, scale1, shift1, tbuf);

  // linear1 + residual -> out (fp32)
  gemm_ch<1><<<dim3(16, 2, CCH), 256, 0, stream>>>(tbuf, w1bf, b1, x, nullptr, out);
}

// Round 3
// 289.453 us; speedup vs baseline: 1.2486x; 1.0132x over previous
//
#include <hip/hip_runtime.h>
#include <hip/hip_bf16.h>

#define NROWS 2048
#define CCH   64
#define FDIM  256
#define CF    16384   // C*F
#define EPSV  1e-3f

typedef __attribute__((ext_vector_type(8))) short  short8;
typedef __attribute__((ext_vector_type(4))) float  f32x4;

__device__ __forceinline__ ushort f2bf(float f) {
  union { float f; unsigned u; } v; v.f = f;
  unsigned r = v.u + 0x7fffu + ((v.u >> 16) & 1u);
  return (ushort)(r >> 16);
}
__device__ __forceinline__ float bf2f(ushort u) {
  union { unsigned u; float f; } v; v.u = ((unsigned)u) << 16;
  return v.f;
}

// ---------------- BN stats (column sums over batch dim) ----------------
__global__ __launch_bounds__(256) void bn_stats_f32(const float* __restrict__ src,
                                                    float* __restrict__ sum,
                                                    float* __restrict__ sumsq) {
  int cb = blockIdx.x * 256 + threadIdx.x;       // float4 col index 0..4095
  int r0 = blockIdx.y * 64;
  const float4* p = (const float4*)src + (size_t)r0 * (CF / 4) + cb;
  float s0 = 0, s1 = 0, s2 = 0, s3 = 0, q0 = 0, q1 = 0, q2 = 0, q3 = 0;
#pragma unroll 8
  for (int i = 0; i < 64; ++i) {
    float4 v = p[(size_t)i * (CF / 4)];
    s0 += v.x; q0 += v.x * v.x;
    s1 += v.y; q1 += v.y * v.y;
    s2 += v.z; q2 += v.z * v.z;
    s3 += v.w; q3 += v.w * v.w;
  }
  int col = cb * 4;
  atomicAdd(&sum[col + 0], s0); atomicAdd(&sum[col + 1], s1);
  atomicAdd(&sum[col + 2], s2); atomicAdd(&sum[col + 3], s3);
  atomicAdd(&sumsq[col + 0], q0); atomicAdd(&sumsq[col + 1], q1);
  atomicAdd(&sumsq[col + 2], q2); atomicAdd(&sumsq[col + 3], q3);
}

__global__ __launch_bounds__(256) void bn_stats_bf16(const ushort* __restrict__ src,
                                                     float* __restrict__ sum,
                                                     float* __restrict__ sumsq) {
  int cb = blockIdx.x * 256 + threadIdx.x;       // uint4 (8 bf16) col index 0..2047
  int r0 = blockIdx.y * 64;
  const uint4* p = (const uint4*)src + (size_t)r0 * (CF / 8) + cb;
  float s[8] = {0, 0, 0, 0, 0, 0, 0, 0};
  float q[8] = {0, 0, 0, 0, 0, 0, 0, 0};
#pragma unroll 4
  for (int i = 0; i < 64; ++i) {
    uint4 v = p[(size_t)i * (CF / 8)];
    unsigned w[4] = {v.x, v.y, v.z, v.w};
#pragma unroll
    for (int j = 0; j < 4; ++j) {
      float a = bf2f((ushort)(w[j] & 0xffffu));
      float b = bf2f((ushort)(w[j] >> 16));
      s[2 * j]     += a; q[2 * j]     += a * a;
      s[2 * j + 1] += b; q[2 * j + 1] += b * b;
    }
  }
  int col = cb * 8;
#pragma unroll
  for (int j = 0; j < 8; ++j) {
    atomicAdd(&sum[col + j], s[j]);
    atomicAdd(&sumsq[col + j], q[j]);
  }
}

__global__ __launch_bounds__(256) void bn_finalize(const float* __restrict__ sum,
                                                   const float* __restrict__ sumsq,
                                                   const float* __restrict__ g,
                                                   const float* __restrict__ be,
                                                   float* __restrict__ scale,
                                                   float* __restrict__ shift) {
  int i = blockIdx.x * 256 + threadIdx.x;        // grid 64
  float mean = sum[i] * (1.0f / NROWS);
  float var  = sumsq[i] * (1.0f / NROWS) - mean * mean;
  float sc   = g[i] * rsqrtf(var + EPSV);
  scale[i] = sc;
  shift[i] = be[i] - mean * sc;
}

// ---------------- BN apply + ReLU -> bf16 ----------------
__global__ __launch_bounds__(256) void bn_apply_f32(const float* __restrict__ x,
                                                    const float* __restrict__ scale,
                                                    const float* __restrict__ shift,
                                                    ushort* __restrict__ o) {
  size_t stride = (size_t)gridDim.x * blockDim.x;
  const size_t total4 = (size_t)NROWS * CF / 4;
  for (size_t i = (size_t)blockIdx.x * 256 + threadIdx.x; i < total4; i += stride) {
    float4 v = ((const float4*)x)[i];
    int col = (int)(i & (CF / 4 - 1)) * 4;
    float a = fmaxf(fmaf(v.x, scale[col + 0], shift[col + 0]), 0.f);
    float b = fmaxf(fmaf(v.y, scale[col + 1], shift[col + 1]), 0.f);
    float c = fmaxf(fmaf(v.z, scale[col + 2], shift[col + 2]), 0.f);
    float d = fmaxf(fmaf(v.w, scale[col + 3], shift[col + 3]), 0.f);
    ushort4 u;
    u.x = f2bf(a); u.y = f2bf(b); u.z = f2bf(c); u.w = f2bf(d);
    ((ushort4*)o)[i] = u;
  }
}

__global__ __launch_bounds__(256) void bn_apply_bf16(const ushort* __restrict__ y,
                                                     const float* __restrict__ scale,
                                                     const float* __restrict__ shift,
                                                     ushort* __restrict__ o) {
  size_t stride = (size_t)gridDim.x * blockDim.x;
  const size_t total8 = (size_t)NROWS * CF / 8;
  for (size_t i = (size_t)blockIdx.x * 256 + threadIdx.x; i < total8; i += stride) {
    uint4 v = ((const uint4*)y)[i];
    int col = (int)(i & (CF / 8 - 1)) * 8;
    unsigned w[4] = {v.x, v.y, v.z, v.w};
    unsigned res[4];
#pragma unroll
    for (int j = 0; j < 4; ++j) {
      float a = fmaxf(fmaf(bf2f((ushort)(w[j] & 0xffffu)), scale[col + 2 * j], shift[col + 2 * j]), 0.f);
      float b = fmaxf(fmaf(bf2f((ushort)(w[j] >> 16)), scale[col + 2 * j + 1], shift[col + 2 * j + 1]), 0.f);
      res[j] = (unsigned)f2bf(a) | ((unsigned)f2bf(b) << 16);
    }
    uint4 r; r.x = res[0]; r.y = res[1]; r.z = res[2]; r.w = res[3];
    ((uint4*)o)[i] = r;
  }
}

// ---------------- weight f32 -> bf16 ----------------
__global__ __launch_bounds__(256) void cvt_f32_bf16(const float* __restrict__ w,
                                                    ushort* __restrict__ o, int n4) {
  size_t stride = (size_t)gridDim.x * blockDim.x;
  for (size_t i = (size_t)blockIdx.x * 256 + threadIdx.x; i < (size_t)n4; i += stride) {
    float4 v = ((const float4*)w)[i];
    ushort4 u;
    u.x = f2bf(v.x); u.y = f2bf(v.y); u.z = f2bf(v.z); u.w = f2bf(v.w);
    ((ushort4*)o)[i] = u;
  }
}

// ---------------- batched channel GEMM, bf16 MFMA ----------------
// Per channel c: out[n,o] = sum_f A[n, c*256+f] * W[c, o, f] (+ bias[c,o])
// W-tile [128 o][256 k] bf16 = 64KB in LDS (staged ONCE, XOR-swizzled).
// A: global -> register fragments directly (no LDS, no K-loop barriers).
// 4 waves, each 32 rows x 128 cols: m=2, n=8 frags, 128 MFMAs/wave.
// Epilogue: C f32 [128][128] reuses the same 64KB LDS; coalesced writeout.
template <int MODE>
__global__ __launch_bounds__(256) void gemm_ch(const ushort* __restrict__ A,
                                               const ushort* __restrict__ W,
                                               const float* __restrict__ bias,
                                               const float* __restrict__ xres,
                                               ushort* __restrict__ Ybf,
                                               float* __restrict__ outf) {
  __shared__ __align__(16) ushort Ws[128 * 256];   // 64KB; reused as C f32[128][128]

  const int c  = blockIdx.z;
  const int bm = blockIdx.x;   // 0..15 (128 rows each)
  const int bn = blockIdx.y;   // 0..1  (128 output cols each)
  const int t  = threadIdx.x;
  const int lane = t & 63, wid = t >> 6;
  const int lm = lane & 15, lg = lane >> 4;

  char* WsB = (char*)Ws;

  // ---- stage W once: 64KB = 256 thr x 16 chunks x 16B. Linear LDS dest,
  // inverse-XOR source: G-byte-in-row = sb ^ ((row&7)<<4); row&7 == t>>5.
  {
    const int srow_lo = t >> 5;                 // 0..7 == row&7 for all chunks
    const int sb  = (t & 31) * 16;              // byte-in-row 0..496
    const int gsb = sb ^ (srow_lo << 4);
    const char* W0 = (const char*)(W + ((size_t)c * FDIM + bn * 128) * FDIM);
#pragma unroll
    for (int i = 0; i < 16; ++i) {
      const int row = i * 8 + srow_lo;
      __builtin_amdgcn_global_load_lds(
          (const __attribute__((address_space(1))) unsigned*)(W0 + (size_t)row * 512 + gsb),
          (__attribute__((address_space(3))) unsigned*)(WsB + row * 512 + sb), 16, 0, 0);
    }
  }

  // bias regs (one per n-frag) — hoisted, hides under W staging
  float bregs[8];
#pragma unroll
  for (int n = 0; n < 8; ++n)
    bregs[n] = bias[c * FDIM + bn * 128 + n * 16 + lm];

  // A fragment base addresses (2 m-frags, 16B per lane per ks)
  const ushort* Ab[2];
#pragma unroll
  for (int m = 0; m < 2; ++m)
    Ab[m] = A + (size_t)(bm * 128 + wid * 32 + m * 16 + lm) * CF + c * FDIM + lg * 8;

  f32x4 acc[2][8];
#pragma unroll
  for (int m = 0; m < 2; ++m)
#pragma unroll
    for (int n = 0; n < 8; ++n) acc[m][n] = (f32x4){0.f, 0.f, 0.f, 0.f};

  __syncthreads();   // W staged (vmcnt(0) drained by compiler before barrier)

  // ---- K loop: no barriers; compiler pipelines A-loads + ds_reads + MFMA
#pragma unroll
  for (int ks = 0; ks < 8; ++ks) {
    short8 af[2];
#pragma unroll
    for (int m = 0; m < 2; ++m)
      af[m] = *(const short8*)(Ab[m] + ks * 32);
    short8 bv[8];
#pragma unroll
    for (int n = 0; n < 8; ++n) {
      const int ro = n * 16 + lm;
      const int byt = (ks * 64 + lg * 16) ^ ((ro & 7) << 4);
      bv[n] = *(const short8*)(WsB + ro * 512 + byt);
    }
#pragma unroll
    for (int m = 0; m < 2; ++m)
#pragma unroll
      for (int n = 0; n < 8; ++n)
        acc[m][n] = __builtin_amdgcn_mfma_f32_16x16x32_bf16(af[m], bv[n], acc[m][n], 0, 0, 0);
  }

  // ---- epilogue phase 1: bias add, C -> LDS (f32, XOR-swizzled)
  __syncthreads();   // all waves done reading Ws
  float* Cs = (float*)WsB;   // [128][128] f32, idx = row*128 + (col ^ (((row>>2)&7)<<2))
#pragma unroll
  for (int m = 0; m < 2; ++m) {
    const int rbase = wid * 32 + m * 16 + lg * 4;
#pragma unroll
    for (int n = 0; n < 8; ++n) {
      const int col = n * 16 + lm;
#pragma unroll
      for (int j = 0; j < 4; ++j) {
        const int row = rbase + j;
        Cs[row * 128 + (col ^ (((row >> 2) & 7) << 2))] = acc[m][n][j] + bregs[n];
      }
    }
  }
  __syncthreads();

  // ---- epilogue phase 2: coalesced writeout (16 thr/row -> contiguous rows)
  const int prow = t >> 4;          // 0..15
  const int pcol = (t & 15) * 8;    // 0..120
#pragma unroll
  for (int rb = 0; rb < 8; ++rb) {
    const int row = rb * 16 + prow;
    const int xd = ((row >> 2) & 7) << 2;
    f32x4 v0 = *(const f32x4*)&Cs[row * 128 + (pcol ^ xd)];
    f32x4 v1 = *(const f32x4*)&Cs[row * 128 + ((pcol + 4) ^ xd)];
    const size_t gofs = (size_t)(bm * 128 + row) * CF + c * FDIM + bn * 128 + pcol;
    if (MODE == 0) {
      uint4 u;
      u.x = (unsigned)f2bf(v0[0]) | ((unsigned)f2bf(v0[1]) << 16);
      u.y = (unsigned)f2bf(v0[2]) | ((unsigned)f2bf(v0[3]) << 16);
      u.z = (unsigned)f2bf(v1[0]) | ((unsigned)f2bf(v1[1]) << 16);
      u.w = (unsigned)f2bf(v1[2]) | ((unsigned)f2bf(v1[3]) << 16);
      *(uint4*)(Ybf + gofs) = u;
    } else {
      float4 x0 = *(const float4*)(xres + gofs);
      float4 x1 = *(const float4*)(xres + gofs + 4);
      float4 o0, o1;
      o0.x = x0.x + v0[0]; o0.y = x0.y + v0[1]; o0.z = x0.z + v0[2]; o0.w = x0.w + v0[3];
      o1.x = x1.x + v1[0]; o1.y = x1.y + v1[1]; o1.z = x1.z + v1[2]; o1.w = x1.w + v1[3];
      *(float4*)(outf + gofs) = o0;
      *(float4*)(outf + gofs + 4) = o1;
    }
  }
}

// ---------------- launch ----------------
extern "C" void kernel_launch(void* const* d_in, const int* in_sizes, int n_in,
                              void* d_out, int out_size, void* d_ws, size_t ws_size,
                              hipStream_t stream) {
  const float* x   = (const float*)d_in[0];
  const float* w0  = (const float*)d_in[1];
  const float* b0  = (const float*)d_in[2];
  const float* w1  = (const float*)d_in[3];
  const float* b1  = (const float*)d_in[4];
  const float* g0  = (const float*)d_in[5];
  const float* be0 = (const float*)d_in[6];
  const float* g1  = (const float*)d_in[7];
  const float* be1 = (const float*)d_in[8];
  float* out = (float*)d_out;

  char* ws = (char*)d_ws;
  const size_t STATS = 16384 * sizeof(float);
  float* sum0   = (float*)(ws + 0 * STATS);
  float* sumsq0 = (float*)(ws + 1 * STATS);
  float* sum1   = (float*)(ws + 2 * STATS);
  float* sumsq1 = (float*)(ws + 3 * STATS);
  float* scale0 = (float*)(ws + 4 * STATS);
  float* shift0 = (float*)(ws + 5 * STATS);
  float* scale1 = (float*)(ws + 6 * STATS);
  float* shift1 = (float*)(ws + 7 * STATS);
  ushort* w0bf = (ushort*)(ws + 8 * STATS);
  ushort* w1bf = w0bf + (size_t)CCH * FDIM * FDIM;
  ushort* tbuf = w1bf + (size_t)CCH * FDIM * FDIM;          // reused for t0 and t1
  ushort* ybf  = tbuf + (size_t)NROWS * CF;

  hipMemsetAsync(ws, 0, 4 * STATS, stream);  // zero the four sum buffers

  const int NW4 = CCH * FDIM * FDIM / 4;
  cvt_f32_bf16<<<1024, 256, 0, stream>>>(w0, w0bf, NW4);
  cvt_f32_bf16<<<1024, 256, 0, stream>>>(w1, w1bf, NW4);

  // BN0 over x
  bn_stats_f32<<<dim3(16, 32), 256, 0, stream>>>(x, sum0, sumsq0);
  bn_finalize<<<64, 256, 0, stream>>>(sum0, sumsq0, g0, be0, scale0, shift0);
  bn_apply_f32<<<2048, 256, 0, stream>>>(x, scale0, shift0, tbuf);

  // linear0 -> ybf (bf16)
  gemm_ch<0><<<dim3(16, 2, CCH), 256, 0, stream>>>(tbuf, w0bf, b0, nullptr, ybf, nullptr);

  // BN1 over ybf
  bn_stats_bf16<<<dim3(8, 32), 256, 0, stream>>>(ybf, sum1, sumsq1);
  bn_finalize<<<64, 256, 0, stream>>>(sum1, sumsq1, g1, be1, scale1, shift1);
  bn_apply_bf16<<<2048, 256, 0, stream>>>(ybf, scale1, shift1, tbuf);

  // linear1 + residual -> out (fp32)
  gemm_ch<1><<<dim3(16, 2, CCH), 256, 0, stream>>>(tbuf, w1bf, b1, x, nullptr, out);
}

// Round 4
// 211.961 us; speedup vs baseline: 1.7051x; 1.3656x over previous
//
#include <hip/hip_runtime.h>
#include <hip/hip_bf16.h>

#define NROWS 2048
#define CCH   64
#define FDIM  256
#define CF    16384   // C*F
#define EPSV  1e-3f

typedef __attribute__((ext_vector_type(8))) short  short8;
typedef __attribute__((ext_vector_type(4))) float  f32x4;

__device__ __forceinline__ ushort f2bf(float f) {
  union { float f; unsigned u; } v; v.f = f;
  unsigned r = v.u + 0x7fffu + ((v.u >> 16) & 1u);
  return (ushort)(r >> 16);
}
__device__ __forceinline__ float bf_lo(unsigned u) {   // low bf16 of packed u32
  union { unsigned u; float f; } v; v.u = u << 16; return v.f;
}
__device__ __forceinline__ float bf_hi(unsigned u) {   // high bf16 of packed u32
  union { unsigned u; float f; } v; v.u = u & 0xffff0000u; return v.f;
}
__device__ __forceinline__ unsigned pk2(float a, float b) {
  __hip_bfloat162 h = __float22bfloat162_rn(float2{a, b});
  union { __hip_bfloat162 h; unsigned u; } cv; cv.h = h; return cv.u;
}
__device__ __forceinline__ void gll16(const void* g, void* l) {
  __builtin_amdgcn_global_load_lds(
      (const __attribute__((address_space(1))) unsigned*)g,
      (__attribute__((address_space(3))) unsigned*)l, 16, 0, 0);
}

// ---------------- BN stats partials (no atomics) ----------------
// grid (16, 32), block 256. partial[by][col]: each thread 4 cols x 64 rows.
__global__ __launch_bounds__(256) void bn_stats_part(const float* __restrict__ src,
                                                     float* __restrict__ ps,
                                                     float* __restrict__ pq) {
  int cb = blockIdx.x * 256 + threadIdx.x;       // float4 col index 0..4095
  int by = blockIdx.y;
  const float4* p = (const float4*)src + (size_t)(by * 64) * (CF / 4) + cb;
  float s0 = 0, s1 = 0, s2 = 0, s3 = 0, q0 = 0, q1 = 0, q2 = 0, q3 = 0;
#pragma unroll 8
  for (int i = 0; i < 64; ++i) {
    float4 v = p[(size_t)i * (CF / 4)];
    s0 += v.x; q0 += v.x * v.x;
    s1 += v.y; q1 += v.y * v.y;
    s2 += v.z; q2 += v.z * v.z;
    s3 += v.w; q3 += v.w * v.w;
  }
  float4 sv; sv.x = s0; sv.y = s1; sv.z = s2; sv.w = s3;
  float4 qv; qv.x = q0; qv.y = q1; qv.z = q2; qv.w = q3;
  ((float4*)(ps + (size_t)by * CF))[cb] = sv;
  ((float4*)(pq + (size_t)by * CF))[cb] = qv;
}

// reduce nparts partials -> scale/shift. grid 64 x 256.
__global__ __launch_bounds__(256) void bn_finalize(const float* __restrict__ ps,
                                                   const float* __restrict__ pq,
                                                   int nparts,
                                                   const float* __restrict__ g,
                                                   const float* __restrict__ be,
                                                   float* __restrict__ scale,
                                                   float* __restrict__ shift) {
  int i = blockIdx.x * 256 + threadIdx.x;
  float s = 0, q = 0;
  for (int j = 0; j < nparts; ++j) {
    s += ps[(size_t)j * CF + i];
    q += pq[(size_t)j * CF + i];
  }
  float mean = s * (1.0f / NROWS);
  float var  = q * (1.0f / NROWS) - mean * mean;
  float sc   = g[i] * rsqrtf(var + EPSV);
  scale[i] = sc;
  shift[i] = be[i] - mean * sc;
}

// ---------------- weight f32 -> bf16 ----------------
__global__ __launch_bounds__(256) void cvt_f32_bf16(const float* __restrict__ w,
                                                    ushort* __restrict__ o, int n4) {
  size_t stride = (size_t)gridDim.x * blockDim.x;
  for (size_t i = (size_t)blockIdx.x * 256 + threadIdx.x; i < (size_t)n4; i += stride) {
    float4 v = ((const float4*)w)[i];
    ushort4 u;
    u.x = f2bf(v.x); u.y = f2bf(v.y); u.z = f2bf(v.z); u.w = f2bf(v.w);
    ((ushort4*)o)[i] = u;
  }
}

// ---------------- fused batched channel GEMM ----------------
// MODE 0: A = relu(x*scale+shift) from f32 x, on the fly -> bf16 frags.
//         Epilogue: ybf = bf16(acc+bias); also BN1 column partial stats.
// MODE 1: A = relu(ybf*scale+shift) from bf16, on the fly.
//         Epilogue: out = xres + acc + bias (direct f32 stores).
// W-tile [128 o][256 k] staged as two 32KB k-halves (overlap half-1 with MFMA).
// 4 waves, each 32 rows x 128 cols: m=2, n=8 frags.
template <int MODE>
__global__ __launch_bounds__(256, 2) void gemm_fused(const void* __restrict__ Asrc,
                                                     const ushort* __restrict__ W,
                                                     const float* __restrict__ bias,
                                                     const float* __restrict__ scale,
                                                     const float* __restrict__ shift,
                                                     const float* __restrict__ xres,
                                                     ushort* __restrict__ Ybf,
                                                     float* __restrict__ outf,
                                                     float* __restrict__ ps1,
                                                     float* __restrict__ pq1) {
  __shared__ __align__(16) ushort Ws[2][128 * 128];   // [k-half][row*128+colk], 64KB
  __shared__ float scl[256], shf[256];                // 2KB
  __shared__ float sstat[2][4][8][16];                // 4KB (MODE0)

  const int t = threadIdx.x;
  const int lane = t & 63, wid = t >> 6;
  const int lm = lane & 15, lg = lane >> 4;

  // bijective XCD swizzle (nwg=2048, 2048%8==0)
  const int h  = blockIdx.x + (blockIdx.y << 4) + (blockIdx.z << 5);
  const int wg = ((h & 7) << 8) | (h >> 3);
  const int bm = wg & 15, bn = (wg >> 4) & 1, c = wg >> 5;

  // scale/shift slice -> LDS
  scl[t] = scale[c * FDIM + t];
  shf[t] = shift[c * FDIM + t];

  // W staging geometry: per half, 32KB = 256thr x 8 chunks x 16B, linear dest
  const int srow = t >> 4;            // 0..15
  const int sb   = (t & 15) * 16;     // 0..240 byte-in-half-row
  const int gsb  = sb ^ ((srow & 7) << 4);
  const char* Wrow = (const char*)(W + ((size_t)c * FDIM + bn * 128) * FDIM);
  char* Ws0 = (char*)&Ws[0][0];
  char* Ws1 = (char*)&Ws[1][0];

#pragma unroll
  for (int i = 0; i < 8; ++i) {
    const int row = i * 16 + srow;
    gll16(Wrow + (size_t)row * 512 + gsb, Ws0 + row * 256 + sb);
  }

  float bregs[8];
#pragma unroll
  for (int n = 0; n < 8; ++n)
    bregs[n] = bias[c * FDIM + bn * 128 + n * 16 + lm];

  const float*  AbF[2];
  const ushort* AbU[2];
#pragma unroll
  for (int m = 0; m < 2; ++m) {
    const size_t rowoff = (size_t)(bm * 128 + wid * 32 + m * 16 + lm) * CF + c * FDIM + lg * 8;
    AbF[m] = (const float*)Asrc + rowoff;
    AbU[m] = (const ushort*)Asrc + rowoff;
  }

  f32x4 acc[2][8];
#pragma unroll
  for (int m = 0; m < 2; ++m)
#pragma unroll
    for (int n = 0; n < 8; ++n) acc[m][n] = (f32x4){0.f, 0.f, 0.f, 0.f};

  __syncthreads();   // half-0 + scl/shf ready

  // issue half-1 staging; its latency hides under ks=0..3 MFMAs
#pragma unroll
  for (int i = 0; i < 8; ++i) {
    const int row = i * 16 + srow;
    gll16(Wrow + (size_t)row * 512 + 256 + gsb, Ws1 + row * 256 + sb);
  }

#define KS_BODY(ksg, WsH, ksl)                                                   \
  {                                                                              \
    float4 sc0 = *(const float4*)&scl[(ksg) * 32 + lg * 8];                      \
    float4 sc1 = *(const float4*)&scl[(ksg) * 32 + lg * 8 + 4];                  \
    float4 sh0 = *(const float4*)&shf[(ksg) * 32 + lg * 8];                      \
    float4 sh1 = *(const float4*)&shf[(ksg) * 32 + lg * 8 + 4];                  \
    short8 af[2];                                                                \
    _Pragma("unroll")                                                            \
    for (int m = 0; m < 2; ++m) {                                                \
      float v0, v1, v2, v3, v4, v5, v6, v7;                                      \
      if (MODE == 0) {                                                           \
        float4 a0 = *(const float4*)(AbF[m] + (ksg) * 32);                       \
        float4 a1 = *(const float4*)(AbF[m] + (ksg) * 32 + 4);                   \
        v0 = a0.x; v1 = a0.y; v2 = a0.z; v3 = a0.w;                              \
        v4 = a1.x; v5 = a1.y; v6 = a1.z; v7 = a1.w;                              \
      } else {                                                                   \
        uint4 u = *(const uint4*)(AbU[m] + (ksg) * 32);                          \
        v0 = bf_lo(u.x); v1 = bf_hi(u.x); v2 = bf_lo(u.y); v3 = bf_hi(u.y);      \
        v4 = bf_lo(u.z); v5 = bf_hi(u.z); v6 = bf_lo(u.w); v7 = bf_hi(u.w);      \
      }                                                                          \
      v0 = fmaxf(fmaf(v0, sc0.x, sh0.x), 0.f);                                   \
      v1 = fmaxf(fmaf(v1, sc0.y, sh0.y), 0.f);                                   \
      v2 = fmaxf(fmaf(v2, sc0.z, sh0.z), 0.f);                                   \
      v3 = fmaxf(fmaf(v3, sc0.w, sh0.w), 0.f);                                   \
      v4 = fmaxf(fmaf(v4, sc1.x, sh1.x), 0.f);                                   \
      v5 = fmaxf(fmaf(v5, sc1.y, sh1.y), 0.f);                                   \
      v6 = fmaxf(fmaf(v6, sc1.z, sh1.z), 0.f);                                   \
      v7 = fmaxf(fmaf(v7, sc1.w, sh1.w), 0.f);                                   \
      union { short8 s; unsigned u[4]; } pkd;                                    \
      pkd.u[0] = pk2(v0, v1); pkd.u[1] = pk2(v2, v3);                            \
      pkd.u[2] = pk2(v4, v5); pkd.u[3] = pk2(v6, v7);                            \
      af[m] = pkd.s;                                                             \
    }                                                                            \
    short8 bv[8];                                                                \
    _Pragma("unroll")                                                            \
    for (int n = 0; n < 8; ++n) {                                                \
      const int ro = n * 16 + lm;                                                \
      const int byt = ((ksl) * 64 + lg * 16) ^ ((ro & 7) << 4);                  \
      bv[n] = *(const short8*)((WsH) + ro * 256 + byt);                          \
    }                                                                            \
    _Pragma("unroll")                                                            \
    for (int m = 0; m < 2; ++m)                                                  \
      _Pragma("unroll")                                                          \
      for (int n = 0; n < 8; ++n)                                                \
        acc[m][n] = __builtin_amdgcn_mfma_f32_16x16x32_bf16(af[m], bv[n],        \
                                                            acc[m][n], 0, 0, 0); \
  }

#pragma unroll
  for (int ks = 0; ks < 4; ++ks) KS_BODY(ks, Ws0, ks)
  __syncthreads();   // half-1 staged (vmcnt drained)
#pragma unroll
  for (int ks = 4; ks < 8; ++ks) KS_BODY(ks, Ws1, ks - 4)

  if (MODE == 0) {
    // ---- BN1 column partial stats from f32 acc (pre-bf16-round) ----
    float s[8], q[8];
#pragma unroll
    for (int n = 0; n < 8; ++n) {
      float ss = 0, qq = 0;
#pragma unroll
      for (int m = 0; m < 2; ++m)
#pragma unroll
        for (int j = 0; j < 4; ++j) {
          float v = acc[m][n][j] + bregs[n];
          ss += v; qq += v * v;
        }
      ss += __shfl_xor(ss, 16); ss += __shfl_xor(ss, 32);
      qq += __shfl_xor(qq, 16); qq += __shfl_xor(qq, 32);
      s[n] = ss; q[n] = qq;
    }
    if (lg == 0) {
#pragma unroll
      for (int n = 0; n < 8; ++n) {
        sstat[0][wid][n][lm] = s[n];
        sstat[1][wid][n][lm] = q[n];
      }
    }
    __syncthreads();   // MFMA ds-reads done + sstat written; Ws reusable

    // ---- C -> LDS (f32, xd swizzle), then coalesced bf16 writeout ----
    float* Cs = (float*)&Ws[0][0];   // [128][128] f32 = 64KB
#pragma unroll
    for (int m = 0; m < 2; ++m) {
      const int rbase = wid * 32 + m * 16 + lg * 4;
#pragma unroll
      for (int n = 0; n < 8; ++n) {
        const int col = n * 16 + lm;
#pragma unroll
        for (int j = 0; j < 4; ++j) {
          const int row = rbase + j;
          Cs[row * 128 + (col ^ (((row >> 2) & 7) << 2))] = acc[m][n][j] + bregs[n];
        }
      }
    }
    __syncthreads();

    const int prow = t >> 4;          // 0..15
    const int pcol = (t & 15) * 8;    // 0..120
#pragma unroll
    for (int rb = 0; rb < 8; ++rb) {
      const int row = rb * 16 + prow;
      const int xd = ((row >> 2) & 7) << 2;
      f32x4 v0 = *(const f32x4*)&Cs[row * 128 + (pcol ^ xd)];
      f32x4 v1 = *(const f32x4*)&Cs[row * 128 + ((pcol + 4) ^ xd)];
      uint4 u;
      u.x = pk2(v0[0], v0[1]); u.y = pk2(v0[2], v0[3]);
      u.z = pk2(v1[0], v1[1]); u.w = pk2(v1[2], v1[3]);
      *(uint4*)(Ybf + (size_t)(bm * 128 + row) * CF + c * FDIM + bn * 128 + pcol) = u;
    }

    // ---- partial stats writeout: 256 thr = 2 stats x 128 cols ----
    {
      const int stat = t >> 7;
      const int idx = t & 127;
      const int n = idx >> 4, lmm = idx & 15;
      float v = sstat[stat][0][n][lmm] + sstat[stat][1][n][lmm] +
                sstat[stat][2][n][lmm] + sstat[stat][3][n][lmm];
      float* dst = stat ? pq1 : ps1;
      dst[(size_t)bm * CF + c * FDIM + bn * 128 + n * 16 + lmm] = v;
    }
  } else {
    // ---- MODE 1: direct f32 stores (64B runs per 16 lanes) ----
#pragma unroll
    for (int n = 0; n < 8; ++n) {
      const int col = c * FDIM + bn * 128 + n * 16 + lm;
      const float bb = bregs[n];
#pragma unroll
      for (int m = 0; m < 2; ++m) {
        const int r0 = bm * 128 + wid * 32 + m * 16 + lg * 4;
#pragma unroll
        for (int j = 0; j < 4; ++j) {
          const size_t gofs = (size_t)(r0 + j) * CF + col;
          outf[gofs] = xres[gofs] + acc[m][n][j] + bb;
        }
      }
    }
  }
}

// ---------------- launch ----------------
extern "C" void kernel_launch(void* const* d_in, const int* in_sizes, int n_in,
                              void* d_out, int out_size, void* d_ws, size_t ws_size,
                              hipStream_t stream) {
  const float* x   = (const float*)d_in[0];
  const float* w0  = (const float*)d_in[1];
  const float* b0  = (const float*)d_in[2];
  const float* w1  = (const float*)d_in[3];
  const float* b1  = (const float*)d_in[4];
  const float* g0  = (const float*)d_in[5];
  const float* be0 = (const float*)d_in[6];
  const float* g1  = (const float*)d_in[7];
  const float* be1 = (const float*)d_in[8];
  float* out = (float*)d_out;

  char* ws = (char*)d_ws;
  float* ps0    = (float*)ws;                         // 32*CF
  float* pq0    = ps0 + (size_t)32 * CF;              // 32*CF
  float* ps1    = pq0 + (size_t)32 * CF;              // 16*CF
  float* pq1    = ps1 + (size_t)16 * CF;              // 16*CF
  float* scale0 = pq1 + (size_t)16 * CF;
  float* shift0 = scale0 + CF;
  float* scale1 = shift0 + CF;
  float* shift1 = scale1 + CF;
  ushort* w0bf = (ushort*)(shift1 + CF);
  ushort* w1bf = w0bf + (size_t)CCH * FDIM * FDIM;
  ushort* ybf  = w1bf + (size_t)CCH * FDIM * FDIM;

  const int NW4 = CCH * FDIM * FDIM / 4;
  cvt_f32_bf16<<<1024, 256, 0, stream>>>(w0, w0bf, NW4);
  cvt_f32_bf16<<<1024, 256, 0, stream>>>(w1, w1bf, NW4);

  // BN0 stats over x (no atomics)
  bn_stats_part<<<dim3(16, 32), 256, 0, stream>>>(x, ps0, pq0);
  bn_finalize<<<64, 256, 0, stream>>>(ps0, pq0, 32, g0, be0, scale0, shift0);

  // linear0 fused: A=relu(bn0(x)), out ybf + BN1 partials
  gemm_fused<0><<<dim3(16, 2, CCH), 256, 0, stream>>>(
      x, w0bf, b0, scale0, shift0, nullptr, ybf, nullptr, ps1, pq1);

  bn_finalize<<<64, 256, 0, stream>>>(ps1, pq1, 16, g1, be1, scale1, shift1);

  // linear1 fused: A=relu(bn1(ybf)), out = x + acc + b1
  gemm_fused<1><<<dim3(16, 2, CCH), 256, 0, stream>>>(
      ybf, w1bf, b1, scale1, shift1, x, nullptr, out, nullptr, nullptr);
}